// Round 1
// baseline (2669.028 us; speedup 1.0000x reference)
//
#include <hip/hip_runtime.h>

#define TT 2048     // sequence length
#define DD 256      // head dim
#define RQ 8        // query rows per block
#define NT 256      // threads per block
#define NITER 30    // bisection iterations (2^-30 << fp32 ulp at |tau|)

#define DOT4(A, Kv, Qv) \
    A = fmaf((Qv).x, (Kv).x, fmaf((Qv).y, (Kv).y, fmaf((Qv).z, (Kv).z, fmaf((Qv).w, (Kv).w, (A)))))

__launch_bounds__(NT, 2)
__global__ void entmax_attn_kernel(const float* __restrict__ Q,
                                   const float* __restrict__ V,
                                   const float* __restrict__ K,
                                   float* __restrict__ Out) {
    extern __shared__ float zsh[];              // [RQ][TT] scores -> weights (64 KB)
    const int tid = threadIdx.x;
    const int b   = blockIdx.x >> 8;            // TT/RQ = 256 blocks per batch
    const int t0  = (blockIdx.x & 255) * RQ;

    const float* __restrict__ Qb = Q + ((size_t)b * TT + t0) * DD;
    const float* __restrict__ Kb = K + (size_t)b * TT * DD;
    const float* __restrict__ Vb = V + (size_t)b * TT * DD;

    // ---------------- Phase 1: z = 0.5 * (Q K^T) ----------------
    // Each thread computes 8 score columns (2 groups of 4). K rows stream
    // through registers; q reads are wave-uniform (scalarizable).
    for (int g = 0; g < 2; ++g) {
        const int c0 = (g << 10) + tid;         // columns c0 + {0,256,512,768}
        const float* k0 = Kb + (size_t)c0 * DD;
        float4 acc[RQ];
        #pragma unroll
        for (int r = 0; r < RQ; ++r) acc[r] = make_float4(0.f, 0.f, 0.f, 0.f);

        for (int d = 0; d < DD; d += 4) {
            const float4 ka = *(const float4*)(k0 + d);
            const float4 kb = *(const float4*)(k0 + 256 * DD + d);
            const float4 kc = *(const float4*)(k0 + 512 * DD + d);
            const float4 kd = *(const float4*)(k0 + 768 * DD + d);
            #pragma unroll
            for (int r = 0; r < RQ; ++r) {
                const float4 qv = *(const float4*)(Qb + r * DD + d);
                DOT4(acc[r].x, ka, qv);
                DOT4(acc[r].y, kb, qv);
                DOT4(acc[r].z, kc, qv);
                DOT4(acc[r].w, kd, qv);
            }
        }
        #pragma unroll
        for (int r = 0; r < RQ; ++r) {
            zsh[r * TT + c0      ] = 0.5f * acc[r].x;
            zsh[r * TT + c0 + 256] = 0.5f * acc[r].y;
            zsh[r * TT + c0 + 512] = 0.5f * acc[r].z;
            zsh[r * TT + c0 + 768] = 0.5f * acc[r].w;
        }
    }
    __syncthreads();

    // ---------------- Phase 2: entmax bisection (in registers) ----------------
    // Wave w handles rows 2w, 2w+1. Row's 2048 z-values -> 32 regs/lane.
    {
        const int wid  = tid >> 6;
        const int lane = tid & 63;
        for (int rr = 0; rr < 2; ++rr) {
            const int r = wid * 2 + rr;
            float* z = zsh + r * TT;
            float zv[32];
            float m = -3.402823466e38f;
            #pragma unroll
            for (int j = 0; j < 32; ++j) {
                zv[j] = z[lane + (j << 6)];
                m = fmaxf(m, zv[j]);
            }
            #pragma unroll
            for (int off = 32; off; off >>= 1) m = fmaxf(m, __shfl_xor(m, off));

            float lo = m - 1.0f, hi = m;
            for (int it = 0; it < NITER; ++it) {
                const float tau = 0.5f * (lo + hi);
                float s = 0.f;
                #pragma unroll
                for (int j = 0; j < 32; ++j) {
                    float t = fmaxf(zv[j] - tau, 0.f);
                    s = fmaf(t, t, s);
                }
                #pragma unroll
                for (int off = 32; off; off >>= 1) s += __shfl_xor(s, off);
                const bool gt = (s - 1.0f) > 0.0f;     // f > 0
                lo = gt ? tau : lo;
                hi = gt ? hi : tau;
            }
            const float tau = 0.5f * (lo + hi);
            float ssum = 0.f;
            #pragma unroll
            for (int j = 0; j < 32; ++j) {
                float t = fmaxf(zv[j] - tau, 0.f);
                ssum = fmaf(t, t, ssum);
            }
            #pragma unroll
            for (int off = 32; off; off >>= 1) ssum += __shfl_xor(ssum, off);
            const float inv = 1.0f / ssum;
            #pragma unroll
            for (int j = 0; j < 32; ++j) {
                float t = fmaxf(zv[j] - tau, 0.f);
                z[lane + (j << 6)] = t * t * inv;      // normalized weight
            }
        }
    }
    __syncthreads();

    // ---------------- Phase 3: Out = W V ----------------
    // Thread -> column pair d2, s-group sg. Weights via wave-uniform b128 reads.
    {
        const int d2 = (tid & 127) * 2;
        const int sg = tid >> 7;
        float2 acc[RQ];
        #pragma unroll
        for (int r = 0; r < RQ; ++r) acc[r] = make_float2(0.f, 0.f);

        for (int sc = 0; sc < TT; sc += 8) {
            const int s0 = sc + sg * 4;
            float4 w4[RQ];
            #pragma unroll
            for (int r = 0; r < RQ; ++r) w4[r] = *(const float4*)&zsh[r * TT + s0];
            #pragma unroll
            for (int js = 0; js < 4; ++js) {
                const float2 v = *(const float2*)(Vb + (size_t)(s0 + js) * DD + d2);
                #pragma unroll
                for (int r = 0; r < RQ; ++r) {
                    const float wv = (js == 0) ? w4[r].x : (js == 1) ? w4[r].y
                                   : (js == 2) ? w4[r].z : w4[r].w;
                    acc[r].x = fmaf(wv, v.x, acc[r].x);
                    acc[r].y = fmaf(wv, v.y, acc[r].y);
                }
            }
        }
        __syncthreads();                        // all weight reads done; reuse LDS
        float* part = zsh;                      // [RQ][256] partial buffer (8 KB)
        if (sg == 1) {
            #pragma unroll
            for (int r = 0; r < RQ; ++r) *(float2*)&part[r * DD + d2] = acc[r];
        }
        __syncthreads();
        if (sg == 0) {
            #pragma unroll
            for (int r = 0; r < RQ; ++r) {
                const float2 p = *(const float2*)&part[r * DD + d2];
                float2 o;
                o.x = acc[r].x + p.x;
                o.y = acc[r].y + p.y;
                *(float2*)&Out[((size_t)b * TT + t0 + r) * DD + d2] = o;
            }
        }
    }
}

extern "C" void kernel_launch(void* const* d_in, const int* in_sizes, int n_in,
                              void* d_out, int out_size, void* d_ws, size_t ws_size,
                              hipStream_t stream) {
    const float* Q = (const float*)d_in[0];   // query
    const float* V = (const float*)d_in[1];   // value (dict order!)
    const float* K = (const float*)d_in[2];   // key
    float* Out = (float*)d_out;
    const int B = in_sizes[0] / (TT * DD);    // 16
    dim3 grid(B * (TT / RQ));
    entmax_attn_kernel<<<grid, NT, RQ * TT * sizeof(float), stream>>>(Q, V, K, Out);
}

// Round 2
// 886.539 us; speedup vs baseline: 3.0106x; 3.0106x over previous
//
#include <hip/hip_runtime.h>

#define TT 2048     // sequence length
#define DD 256      // head dim
#define RQ 16       // query rows per block (main kernel)
#define NT 512      // 8 waves
#define NITER 30

typedef __attribute__((ext_vector_type(4))) float f32x4;
typedef __attribute__((ext_vector_type(8))) short short8;

__device__ inline unsigned short f2bf(float x) {     // RTN fp32 -> bf16
    unsigned u = __float_as_uint(x);
    return (unsigned short)((u + 0x7fffu + ((u >> 16) & 1u)) >> 16);
}
__device__ inline float bf2f(unsigned short h) {
    return __uint_as_float((unsigned)h << 16);
}

// ---------------- helper: K -> 0.5*K split to bf16 hi/lo ----------------
__global__ __launch_bounds__(256) void split_k_kernel(const float* __restrict__ K,
        unsigned short* __restrict__ Kh, unsigned short* __restrict__ Kl, int n4) {
    int i = blockIdx.x * 256 + threadIdx.x;
    const int stride = gridDim.x * 256;
    for (; i < n4; i += stride) {
        float4 v = ((const float4*)K)[i];
        float x0 = 0.5f * v.x, x1 = 0.5f * v.y, x2 = 0.5f * v.z, x3 = 0.5f * v.w;
        unsigned short h0 = f2bf(x0), h1 = f2bf(x1), h2 = f2bf(x2), h3 = f2bf(x3);
        unsigned short l0 = f2bf(x0 - bf2f(h0)), l1 = f2bf(x1 - bf2f(h1));
        unsigned short l2 = f2bf(x2 - bf2f(h2)), l3 = f2bf(x3 - bf2f(h3));
        uint2 hv, lv;
        hv.x = (unsigned)h0 | ((unsigned)h1 << 16); hv.y = (unsigned)h2 | ((unsigned)h3 << 16);
        lv.x = (unsigned)l0 | ((unsigned)l1 << 16); lv.y = (unsigned)l2 | ((unsigned)l3 << 16);
        ((uint2*)Kh)[i] = hv;
        ((uint2*)Kl)[i] = lv;
    }
}

// ---------------- helper: V[b][t][d] -> Vt[b][d][t] bf16 ----------------
__global__ __launch_bounds__(256) void transpose_v_kernel(const float* __restrict__ V,
                                                          unsigned short* __restrict__ Vt) {
    __shared__ float tile[64][65];
    const int tt0 = blockIdx.x * 64, dd0 = blockIdx.y * 64, b = blockIdx.z;
    const int t = threadIdx.x;
    const float* src = V + ((size_t)b * TT + tt0) * DD + dd0;
    const int r0 = t >> 4, c4 = (t & 15) * 4;
    #pragma unroll
    for (int i = 0; i < 4; ++i) {
        float4 v = *(const float4*)(src + (size_t)(r0 + i * 16) * DD + c4);
        tile[r0 + i * 16][c4 + 0] = v.x; tile[r0 + i * 16][c4 + 1] = v.y;
        tile[r0 + i * 16][c4 + 2] = v.z; tile[r0 + i * 16][c4 + 3] = v.w;
    }
    __syncthreads();
    const int d = t >> 2, ts = (t & 3) * 16;
    unsigned out[8];
    #pragma unroll
    for (int j = 0; j < 8; ++j) {
        unsigned short a = f2bf(tile[ts + 2 * j][d]);
        unsigned short c = f2bf(tile[ts + 2 * j + 1][d]);
        out[j] = (unsigned)a | ((unsigned)c << 16);
    }
    uint4* dst = (uint4*)(Vt + ((size_t)b * DD + dd0 + d) * TT + tt0 + ts);
    uint4 o0; o0.x = out[0]; o0.y = out[1]; o0.z = out[2]; o0.w = out[3];
    uint4 o1; o1.x = out[4]; o1.y = out[5]; o1.z = out[6]; o1.w = out[7];
    dst[0] = o0; dst[1] = o1;
}

// ---------------- main fused kernel ----------------
#define LDS_BYTES (RQ * TT * 4 + RQ * 64 * 4)   // 128KB z/w + 4KB cand

__launch_bounds__(NT, 2)
__global__ void entmax_mfma_kernel(const float* __restrict__ Q,
                                   const unsigned short* __restrict__ Kh,
                                   const unsigned short* __restrict__ Kl,
                                   const unsigned short* __restrict__ Vt,
                                   float* __restrict__ Out) {
    extern __shared__ char smem[];
    float* zsh   = (float*)smem;                  // [RQ][TT] fp32 scores
    float* cands = (float*)(smem + RQ * TT * 4);  // [RQ][64] candidate values

    const int tid  = threadIdx.x;
    const int wid  = tid >> 6, lane = tid & 63;
    const int l15  = lane & 15, ag = lane >> 4;

    // XCD-aware swizzle: each XCD (blockIdx%8) walks 2 whole batches sequentially
    const int lb = (blockIdx.x & 7) * 256 + (blockIdx.x >> 3);
    const int b  = lb >> 7;
    const int t0 = (lb & 127) * RQ;

    // ---------- Phase 1: z = 0.5*Q*K^T via bf16 hi/lo split MFMA ----------
    {
        const int cstripe = wid * 256;
        const float* qrow = Q + (size_t)(b * TT + t0 + l15) * DD;
        const unsigned short* pKh = Kh + (size_t)b * TT * DD + (size_t)(cstripe + l15) * DD;
        const unsigned short* pKl = Kl + (size_t)b * TT * DD + (size_t)(cstripe + l15) * DD;
        f32x4 acc[16];
        #pragma unroll
        for (int ct = 0; ct < 16; ++ct)
            #pragma unroll
            for (int rg = 0; rg < 4; ++rg) acc[ct][rg] = 0.0f;

        for (int kk = 0; kk < 8; ++kk) {
            const int d0 = kk * 32 + ag * 8;
            float4 qa = *(const float4*)(qrow + d0);
            float4 qb = *(const float4*)(qrow + d0 + 4);
            float qf[8] = {qa.x, qa.y, qa.z, qa.w, qb.x, qb.y, qb.z, qb.w};
            short8 ah, al;
            #pragma unroll
            for (int i = 0; i < 8; ++i) {
                unsigned short h = f2bf(qf[i]);
                ah[i] = (short)h;
                al[i] = (short)f2bf(qf[i] - bf2f(h));
            }
            #pragma unroll
            for (int ct = 0; ct < 16; ++ct) {
                short8 bh = *(const short8*)(pKh + ct * 16 * DD + d0);
                short8 bl = *(const short8*)(pKl + ct * 16 * DD + d0);
                acc[ct] = __builtin_amdgcn_mfma_f32_16x16x32_bf16(ah, bh, acc[ct], 0, 0, 0);
                acc[ct] = __builtin_amdgcn_mfma_f32_16x16x32_bf16(ah, bl, acc[ct], 0, 0, 0);
                acc[ct] = __builtin_amdgcn_mfma_f32_16x16x32_bf16(al, bh, acc[ct], 0, 0, 0);
            }
        }
        // C/D layout: col = lane&15, row = (lane>>4)*4 + reg  [m89-verified]
        #pragma unroll
        for (int ct = 0; ct < 16; ++ct)
            #pragma unroll
            for (int rg = 0; rg < 4; ++rg)
                zsh[(ag * 4 + rg) * TT + cstripe + ct * 16 + l15] = acc[ct][rg];
    }
    __syncthreads();

    // ---------- Phase 2: entmax bisection (candidate-compacted) ----------
    for (int rr = 0; rr < 2; ++rr) {
        const int r = wid * 2 + rr;
        float zv[32];
        float m = -3.402823466e38f;
        #pragma unroll
        for (int j = 0; j < 32; ++j) {
            zv[j] = zsh[r * TT + lane + j * 64];
            m = fmaxf(m, zv[j]);
        }
        #pragma unroll
        for (int off = 32; off; off >>= 1) m = fmaxf(m, __shfl_xor(m, off));
        const float thr = m - 1.0f;                 // tau >= m-1 always: z<=thr is weight-0
        int cnt = 0;
        #pragma unroll
        for (int j = 0; j < 32; ++j) cnt += (zv[j] > thr) ? 1 : 0;
        int inc = cnt;
        #pragma unroll
        for (int off = 1; off < 64; off <<= 1) {
            int v = __shfl_up(inc, off);
            if (lane >= off) inc += v;
        }
        const int total = __shfl(inc, 63);

        float lo = thr, hi = m, tau, ssum;
        if (total <= 64) {                           // fast path (virtually always)
            int o = inc - cnt;
            #pragma unroll
            for (int j = 0; j < 32; ++j)
                if (zv[j] > thr) cands[r * 64 + (o++)] = zv[j];
            const float cv = (lane < total) ? cands[r * 64 + lane] : -3.402823466e38f;
            for (int it = 0; it < NITER; ++it) {
                tau = 0.5f * (lo + hi);
                float t = fmaxf(cv - tau, 0.0f);
                float s = t * t;
                #pragma unroll
                for (int off = 32; off; off >>= 1) s += __shfl_xor(s, off);
                const bool gt = s > 1.0f;
                lo = gt ? tau : lo;
                hi = gt ? hi : tau;
            }
            tau = 0.5f * (lo + hi);
            float t = fmaxf(cv - tau, 0.0f);
            ssum = t * t;
            #pragma unroll
            for (int off = 32; off; off >>= 1) ssum += __shfl_xor(ssum, off);
        } else {                                     // full-scan fallback
            for (int it = 0; it < NITER; ++it) {
                tau = 0.5f * (lo + hi);
                float s = 0.f;
                #pragma unroll
                for (int j = 0; j < 32; ++j) {
                    float t = fmaxf(zv[j] - tau, 0.0f);
                    s = fmaf(t, t, s);
                }
                #pragma unroll
                for (int off = 32; off; off >>= 1) s += __shfl_xor(s, off);
                const bool gt = s > 1.0f;
                lo = gt ? tau : lo;
                hi = gt ? hi : tau;
            }
            tau = 0.5f * (lo + hi);
            ssum = 0.f;
            #pragma unroll
            for (int j = 0; j < 32; ++j) {
                float t = fmaxf(zv[j] - tau, 0.0f);
                ssum = fmaf(t, t, ssum);
            }
            #pragma unroll
            for (int off = 32; off; off >>= 1) ssum += __shfl_xor(ssum, off);
        }
        const float inv = 1.0f / ssum;
        // write weights bf16 in-place over dead z row r, XOR-swizzled (16B granule)
        const int sw = (r & 7) << 4;
        #pragma unroll
        for (int j = 0; j < 32; ++j) {
            const int c = lane + j * 64;
            float t = fmaxf(zv[j] - tau, 0.0f);
            *(unsigned short*)(smem + r * 8192 + ((2 * c) ^ sw)) = f2bf(t * t * inv);
        }
    }
    __syncthreads();

    // ---------- Phase 3: Out = W V (bf16 MFMA, W from swizzled LDS) ----------
    {
        const int dstripe = wid * 32;
        const unsigned short* pV = Vt + (size_t)b * DD * TT + (size_t)(dstripe + l15) * TT + ag * 8;
        f32x4 oacc[2];
        #pragma unroll
        for (int ct = 0; ct < 2; ++ct)
            #pragma unroll
            for (int rg = 0; rg < 4; ++rg) oacc[ct][rg] = 0.0f;
        const int r = l15;                           // A-frag row
        const int sw = (r & 7) << 4;
        for (int kk = 0; kk < 64; ++kk) {
            const int kb = kk * 64 + ag * 16;        // byte offset of 2*k
            short8 wf = *(const short8*)(smem + r * 8192 + (kb ^ sw));
            #pragma unroll
            for (int ct = 0; ct < 2; ++ct) {
                short8 vf = *(const short8*)(pV + ct * 16 * TT + kk * 32);
                oacc[ct] = __builtin_amdgcn_mfma_f32_16x16x32_bf16(wf, vf, oacc[ct], 0, 0, 0);
            }
        }
        #pragma unroll
        for (int ct = 0; ct < 2; ++ct)
            #pragma unroll
            for (int rg = 0; rg < 4; ++rg)
                Out[(size_t)(b * TT + t0 + ag * 4 + rg) * DD + dstripe + ct * 16 + l15] =
                    oacc[ct][rg];
    }
}

// ---------------- round-1 kernel kept as ws-size fallback ----------------
#define DOT4(A, Kv, Qv) \
    A = fmaf((Qv).x, (Kv).x, fmaf((Qv).y, (Kv).y, fmaf((Qv).z, (Kv).z, fmaf((Qv).w, (Kv).w, (A)))))

__launch_bounds__(256, 2)
__global__ void entmax_fallback_kernel(const float* __restrict__ Q,
                                       const float* __restrict__ V,
                                       const float* __restrict__ K,
                                       float* __restrict__ Out) {
    extern __shared__ float zshf[];
    const int tid = threadIdx.x;
    const int b   = blockIdx.x >> 8;
    const int t0  = (blockIdx.x & 255) * 8;
    const float* Qb = Q + ((size_t)b * TT + t0) * DD;
    const float* Kb = K + (size_t)b * TT * DD;
    const float* Vb = V + (size_t)b * TT * DD;
    for (int g = 0; g < 2; ++g) {
        const int c0 = (g << 10) + tid;
        const float* k0 = Kb + (size_t)c0 * DD;
        float4 acc[8];
        #pragma unroll
        for (int r = 0; r < 8; ++r) acc[r] = make_float4(0.f, 0.f, 0.f, 0.f);
        for (int d = 0; d < DD; d += 4) {
            const float4 ka = *(const float4*)(k0 + d);
            const float4 kb = *(const float4*)(k0 + 256 * DD + d);
            const float4 kc = *(const float4*)(k0 + 512 * DD + d);
            const float4 kd = *(const float4*)(k0 + 768 * DD + d);
            #pragma unroll
            for (int r = 0; r < 8; ++r) {
                const float4 qv = *(const float4*)(Qb + r * DD + d);
                DOT4(acc[r].x, ka, qv); DOT4(acc[r].y, kb, qv);
                DOT4(acc[r].z, kc, qv); DOT4(acc[r].w, kd, qv);
            }
        }
        #pragma unroll
        for (int r = 0; r < 8; ++r) {
            zshf[r * TT + c0      ] = 0.5f * acc[r].x;
            zshf[r * TT + c0 + 256] = 0.5f * acc[r].y;
            zshf[r * TT + c0 + 512] = 0.5f * acc[r].z;
            zshf[r * TT + c0 + 768] = 0.5f * acc[r].w;
        }
    }
    __syncthreads();
    {
        const int wid = tid >> 6, lane = tid & 63;
        for (int rr = 0; rr < 2; ++rr) {
            const int r = wid * 2 + rr;
            float* z = zshf + r * TT;
            float zv[32];
            float m = -3.402823466e38f;
            #pragma unroll
            for (int j = 0; j < 32; ++j) { zv[j] = z[lane + (j << 6)]; m = fmaxf(m, zv[j]); }
            #pragma unroll
            for (int off = 32; off; off >>= 1) m = fmaxf(m, __shfl_xor(m, off));
            float lo = m - 1.0f, hi = m;
            for (int it = 0; it < NITER; ++it) {
                const float tau = 0.5f * (lo + hi);
                float s = 0.f;
                #pragma unroll
                for (int j = 0; j < 32; ++j) { float t = fmaxf(zv[j] - tau, 0.f); s = fmaf(t, t, s); }
                #pragma unroll
                for (int off = 32; off; off >>= 1) s += __shfl_xor(s, off);
                const bool gt = (s - 1.0f) > 0.0f;
                lo = gt ? tau : lo; hi = gt ? hi : tau;
            }
            const float tau = 0.5f * (lo + hi);
            float ssum = 0.f;
            #pragma unroll
            for (int j = 0; j < 32; ++j) { float t = fmaxf(zv[j] - tau, 0.f); ssum = fmaf(t, t, ssum); }
            #pragma unroll
            for (int off = 32; off; off >>= 1) ssum += __shfl_xor(ssum, off);
            const float inv = 1.0f / ssum;
            #pragma unroll
            for (int j = 0; j < 32; ++j) {
                float t = fmaxf(zv[j] - tau, 0.f);
                z[lane + (j << 6)] = t * t * inv;
            }
        }
    }
    __syncthreads();
    {
        const int d2 = (tid & 127) * 2;
        const int sg = tid >> 7;
        float2 acc[8];
        #pragma unroll
        for (int r = 0; r < 8; ++r) acc[r] = make_float2(0.f, 0.f);
        for (int sc = 0; sc < TT; sc += 8) {
            const int s0 = sc + sg * 4;
            float4 w4[8];
            #pragma unroll
            for (int r = 0; r < 8; ++r) w4[r] = *(const float4*)&zshf[r * TT + s0];
            #pragma unroll
            for (int js = 0; js < 4; ++js) {
                const float2 v = *(const float2*)(Vb + (size_t)(s0 + js) * DD + d2);
                #pragma unroll
                for (int r = 0; r < 8; ++r) {
                    const float wv = (js == 0) ? w4[r].x : (js == 1) ? w4[r].y
                                   : (js == 2) ? w4[r].z : w4[r].w;
                    acc[r].x = fmaf(wv, v.x, acc[r].x);
                    acc[r].y = fmaf(wv, v.y, acc[r].y);
                }
            }
        }
        __syncthreads();
        float* part = zshf;
        if (sg == 1) {
            #pragma unroll
            for (int r = 0; r < 8; ++r) *(float2*)&part[r * DD + d2] = acc[r];
        }
        __syncthreads();
        if (sg == 0) {
            #pragma unroll
            for (int r = 0; r < 8; ++r) {
                const float2 p = *(const float2*)&part[r * DD + d2];
                float2 o; o.x = acc[r].x + p.x; o.y = acc[r].y + p.y;
                *(float2*)&Out[((size_t)b * TT + t0 + r) * DD + d2] = o;
            }
        }
    }
}

extern "C" void kernel_launch(void* const* d_in, const int* in_sizes, int n_in,
                              void* d_out, int out_size, void* d_ws, size_t ws_size,
                              hipStream_t stream) {
    const float* Q = (const float*)d_in[0];   // query
    const float* V = (const float*)d_in[1];   // value (dict order!)
    const float* K = (const float*)d_in[2];   // key
    float* Out = (float*)d_out;
    const int B = in_sizes[0] / (TT * DD);
    const size_t NE = (size_t)B * TT * DD;
    const size_t need = NE * 2 * 3;           // Kh + Kl + Vt (bf16 each)

    if (ws_size < need) {                     // defensive fallback (round-1 kernel)
        entmax_fallback_kernel<<<dim3(B * (TT / 8)), 256, 8 * TT * sizeof(float), stream>>>(
            Q, V, K, Out);
        return;
    }

    unsigned short* Kh = (unsigned short*)d_ws;
    unsigned short* Kl = Kh + NE;
    unsigned short* Vt = Kl + NE;

    split_k_kernel<<<2048, 256, 0, stream>>>(K, Kh, Kl, (int)(NE / 4));
    transpose_v_kernel<<<dim3(TT / 64, DD / 64, B), 256, 0, stream>>>(V, Vt);

    (void)hipFuncSetAttribute((const void*)entmax_mfma_kernel,
                              hipFuncAttributeMaxDynamicSharedMemorySize, LDS_BYTES);
    entmax_mfma_kernel<<<dim3(B * (TT / RQ)), NT, LDS_BYTES, stream>>>(Q, Kh, Kl, Vt, Out);
}

// Round 3
// 572.607 us; speedup vs baseline: 4.6612x; 1.5483x over previous
//
#include <hip/hip_runtime.h>

#define TT 2048     // sequence length
#define DD 256      // head dim
#define RQ 16       // query rows per block
#define NT 512      // 8 waves
#define NITER 30    // bisection iterations
#define CAP 64      // max candidates per row on the fast path

typedef __attribute__((ext_vector_type(4))) float f32x4;
typedef __attribute__((ext_vector_type(8))) short short8;

__device__ inline unsigned short f2bf(float x) {     // RTN fp32 -> bf16
    unsigned u = __float_as_uint(x);
    return (unsigned short)((u + 0x7fffu + ((u >> 16) & 1u)) >> 16);
}
__device__ inline float bf2f(unsigned short h) {
    return __uint_as_float((unsigned)h << 16);
}

// ---------------- helper: K -> 0.5*K split to bf16 hi/lo ----------------
__global__ __launch_bounds__(256) void split_k_kernel(const float* __restrict__ K,
        unsigned short* __restrict__ Kh, unsigned short* __restrict__ Kl, int n4) {
    int i = blockIdx.x * 256 + threadIdx.x;
    const int stride = gridDim.x * 256;
    for (; i < n4; i += stride) {
        float4 v = ((const float4*)K)[i];
        float x0 = 0.5f * v.x, x1 = 0.5f * v.y, x2 = 0.5f * v.z, x3 = 0.5f * v.w;
        unsigned short h0 = f2bf(x0), h1 = f2bf(x1), h2 = f2bf(x2), h3 = f2bf(x3);
        unsigned short l0 = f2bf(x0 - bf2f(h0)), l1 = f2bf(x1 - bf2f(h1));
        unsigned short l2 = f2bf(x2 - bf2f(h2)), l3 = f2bf(x3 - bf2f(h3));
        uint2 hv, lv;
        hv.x = (unsigned)h0 | ((unsigned)h1 << 16); hv.y = (unsigned)h2 | ((unsigned)h3 << 16);
        lv.x = (unsigned)l0 | ((unsigned)l1 << 16); lv.y = (unsigned)l2 | ((unsigned)l3 << 16);
        ((uint2*)Kh)[i] = hv;
        ((uint2*)Kl)[i] = lv;
    }
}

// ---------------- main fused kernel ----------------
__launch_bounds__(NT, 4)
__global__ void entmax_sparse_kernel(const float* __restrict__ Q,
                                     const unsigned short* __restrict__ Kh,
                                     const unsigned short* __restrict__ Kl,
                                     const float* __restrict__ V,
                                     float* __restrict__ Out) {
    __shared__ float wpart[RQ][8];      // per-wave row-max partials
    __shared__ float rowmax[RQ];
    __shared__ int   cnt8[RQ][8];       // per (row, wave) candidate count
    __shared__ int   rowtotal[RQ];      // total candidates (or -1 = handled by slow path)
    __shared__ int   widx[RQ][CAP];     // candidate column indices
    __shared__ float wcv[RQ][CAP];      // candidate z values -> weights
    __shared__ float fbz[TT];           // slow-path z/weight row buffer
    __shared__ int   ovf;

    const int tid = threadIdx.x;
    const int wid = tid >> 6, lane = tid & 63;
    const int l15 = lane & 15, ag = lane >> 4;

    if (tid < RQ * 8) ((int*)cnt8)[tid] = 0;
    if (tid == 0) ovf = 0;

    // XCD swizzle: each XCD walks 2 whole batches sequentially (K/V L2-resident)
    const int lb = (blockIdx.x & 7) * 256 + (blockIdx.x >> 3);
    const int b  = lb >> 7;
    const int t0 = (lb & 127) * RQ;

    // ---------- Phase 1: z = 0.5*Q*K^T via bf16 hi/lo split MFMA ----------
    const int cstripe = wid * 256;
    f32x4 acc[16];
    {
        const float* qrow = Q + (size_t)(b * TT + t0 + l15) * DD;
        const unsigned short* pKh = Kh + (size_t)b * TT * DD + (size_t)(cstripe + l15) * DD;
        const unsigned short* pKl = Kl + (size_t)b * TT * DD + (size_t)(cstripe + l15) * DD;
        #pragma unroll
        for (int ct = 0; ct < 16; ++ct)
            #pragma unroll
            for (int rg = 0; rg < 4; ++rg) acc[ct][rg] = 0.0f;

        for (int kk = 0; kk < 8; ++kk) {
            const int d0 = kk * 32 + ag * 8;
            float4 qa = *(const float4*)(qrow + d0);
            float4 qb = *(const float4*)(qrow + d0 + 4);
            float qf[8] = {qa.x, qa.y, qa.z, qa.w, qb.x, qb.y, qb.z, qb.w};
            short8 ah, al;
            #pragma unroll
            for (int i = 0; i < 8; ++i) {
                unsigned short h = f2bf(qf[i]);
                ah[i] = (short)h;
                al[i] = (short)f2bf(qf[i] - bf2f(h));
            }
            #pragma unroll
            for (int ct = 0; ct < 16; ++ct) {
                short8 bh = *(const short8*)(pKh + ct * 16 * DD + d0);
                short8 bl = *(const short8*)(pKl + ct * 16 * DD + d0);
                acc[ct] = __builtin_amdgcn_mfma_f32_16x16x32_bf16(ah, bh, acc[ct], 0, 0, 0);
                acc[ct] = __builtin_amdgcn_mfma_f32_16x16x32_bf16(ah, bl, acc[ct], 0, 0, 0);
                acc[ct] = __builtin_amdgcn_mfma_f32_16x16x32_bf16(al, bh, acc[ct], 0, 0, 0);
            }
        }
        // per-row max from registers: row = ag*4+rg, col = cstripe + ct*16 + l15
        #pragma unroll
        for (int rg = 0; rg < 4; ++rg) {
            float m = -3.402823466e38f;
            #pragma unroll
            for (int ct = 0; ct < 16; ++ct) m = fmaxf(m, acc[ct][rg]);
            m = fmaxf(m, __shfl_xor(m, 1));
            m = fmaxf(m, __shfl_xor(m, 2));
            m = fmaxf(m, __shfl_xor(m, 4));
            m = fmaxf(m, __shfl_xor(m, 8));
            if (l15 == 0) wpart[ag * 4 + rg][wid] = m;
        }
    }
    __syncthreads();
    if (tid < RQ) {
        float m = wpart[tid][0];
        #pragma unroll
        for (int w = 1; w < 8; ++w) m = fmaxf(m, wpart[tid][w]);
        rowmax[tid] = m;
    }
    __syncthreads();

    // ---------- Compaction: deterministic ballot-ranked candidate lists ----------
    const unsigned long long grpmask = 0xFFFFULL << (ag * 16);
    const unsigned long long lowmask = (lane == 0) ? 0ULL : ((~0ULL) >> (64 - lane));
    #pragma unroll
    for (int rg = 0; rg < 4; ++rg) {
        const int row = ag * 4 + rg;
        const float thr = rowmax[row] - 1.0f;
        int run = 0;
        #pragma unroll
        for (int ct = 0; ct < 16; ++ct) {
            unsigned long long ball = __ballot(acc[ct][rg] > thr) & grpmask;
            run += __popcll(ball);
        }
        if (l15 == 0) cnt8[row][wid] = run;
    }
    __syncthreads();
    #pragma unroll
    for (int rg = 0; rg < 4; ++rg) {
        const int row = ag * 4 + rg;
        const float thr = rowmax[row] - 1.0f;
        int bs = 0, tot = 0;
        #pragma unroll
        for (int w = 0; w < 8; ++w) {
            const int c = cnt8[row][w];
            if (w < wid) bs += c;
            tot += c;
        }
        if (wid == 0 && l15 == 0) {
            rowtotal[row] = tot;
            if (tot > CAP) ovf = 1;
        }
        if (tot <= CAP) {
            int run = bs;
            #pragma unroll
            for (int ct = 0; ct < 16; ++ct) {
                const bool c = acc[ct][rg] > thr;
                unsigned long long ball = __ballot(c) & grpmask;
                if (c) {
                    const int pos = run + (int)__popcll(ball & lowmask);
                    widx[row][pos] = cstripe + ct * 16 + l15;
                    wcv[row][pos]  = acc[ct][rg];
                }
                run += __popcll(ball);
            }
        }
    }
    __syncthreads();

    // ---------- Phase 2: bisection on compacted candidates ----------
    #pragma unroll
    for (int rr = 0; rr < 2; ++rr) {
        const int r = wid * 2 + rr;
        const int n = rowtotal[r];
        if (n <= CAP) {
            const float m = rowmax[r];
            const float cv = (lane < n) ? wcv[r][lane] : -3.402823466e38f;
            float lo = m - 1.0f, hi = m, tau;
            for (int it = 0; it < NITER; ++it) {
                tau = 0.5f * (lo + hi);
                float t = fmaxf(cv - tau, 0.0f);
                float s = t * t;
                #pragma unroll
                for (int off = 32; off; off >>= 1) s += __shfl_xor(s, off);
                const bool gt = s > 1.0f;
                lo = gt ? tau : lo;
                hi = gt ? hi : tau;
            }
            tau = 0.5f * (lo + hi);
            float t = fmaxf(cv - tau, 0.0f);
            float ssum = t * t;
            #pragma unroll
            for (int off = 32; off; off >>= 1) ssum += __shfl_xor(ssum, off);
            const float inv = 1.0f / ssum;
            if (lane < n) wcv[r][lane] = t * t * inv;
        }
    }
    __syncthreads();

    // ---------- Slow path (p ~ 0): wave 0 handles overflowing rows ----------
    if (ovf && wid == 0) {
        for (int r = 0; r < RQ; ++r) {
            if (rowtotal[r] <= CAP) continue;
            const float* qr = Q + (size_t)(b * TT + t0 + r) * DD;
            for (int c = lane; c < TT; c += 64) {
                const unsigned short* ph = Kh + ((size_t)b * TT + c) * DD;
                const unsigned short* pl = Kl + ((size_t)b * TT + c) * DD;
                float a = 0.0f;
                for (int d = 0; d < DD; ++d)
                    a = fmaf(qr[d], bf2f(ph[d]) + bf2f(pl[d]), a);
                fbz[c] = a;
            }
            __threadfence_block();
            float m = -3.402823466e38f;
            for (int c = lane; c < TT; c += 64) m = fmaxf(m, fbz[c]);
            #pragma unroll
            for (int off = 32; off; off >>= 1) m = fmaxf(m, __shfl_xor(m, off));
            float lo = m - 1.0f, hi = m, tau;
            for (int it = 0; it < NITER; ++it) {
                tau = 0.5f * (lo + hi);
                float s = 0.0f;
                for (int c = lane; c < TT; c += 64) {
                    float t = fmaxf(fbz[c] - tau, 0.0f);
                    s = fmaf(t, t, s);
                }
                #pragma unroll
                for (int off = 32; off; off >>= 1) s += __shfl_xor(s, off);
                const bool gt = s > 1.0f;
                lo = gt ? tau : lo;
                hi = gt ? hi : tau;
            }
            tau = 0.5f * (lo + hi);
            float ssum = 0.0f;
            for (int c = lane; c < TT; c += 64) {
                float t = fmaxf(fbz[c] - tau, 0.0f);
                ssum = fmaf(t, t, ssum);
            }
            #pragma unroll
            for (int off = 32; off; off >>= 1) ssum += __shfl_xor(ssum, off);
            const float inv = 1.0f / ssum;
            const int d4 = lane * 4;
            float4 o = make_float4(0.f, 0.f, 0.f, 0.f);
            for (int s = 0; s < TT; ++s) {
                float t = fmaxf(fbz[s] - tau, 0.0f);
                const float w = t * t * inv;
                if (w > 0.0f) {
                    const float4 v = *(const float4*)(V + ((size_t)b * TT + s) * DD + d4);
                    o.x = fmaf(w, v.x, o.x); o.y = fmaf(w, v.y, o.y);
                    o.z = fmaf(w, v.z, o.z); o.w = fmaf(w, v.w, o.w);
                }
            }
            *(float4*)(Out + ((size_t)(b * TT + t0 + r)) * DD + d4) = o;
            if (lane == 0) rowtotal[r] = -1;
            __threadfence_block();
        }
    }
    __syncthreads();

    // ---------- Phase 3: sparse PV gather (fp32) ----------
    #pragma unroll
    for (int rr = 0; rr < 2; ++rr) {
        const int r = wid * 2 + rr;
        const int n = rowtotal[r];
        if (n < 0) continue;                      // handled by slow path
        const int d4 = lane * 4;
        float4 o = make_float4(0.f, 0.f, 0.f, 0.f);
        for (int i = 0; i < n; ++i) {
            const float wv = wcv[r][i];
            const int   s  = widx[r][i];
            const float4 v = *(const float4*)(V + ((size_t)b * TT + s) * DD + d4);
            o.x = fmaf(wv, v.x, o.x); o.y = fmaf(wv, v.y, o.y);
            o.z = fmaf(wv, v.z, o.z); o.w = fmaf(wv, v.w, o.w);
        }
        *(float4*)(Out + ((size_t)(b * TT + t0 + r)) * DD + d4) = o;
    }
}

// ---------------- round-1 kernel kept as ws-size fallback ----------------
#define DOT4(A, Kv, Qv) \
    A = fmaf((Qv).x, (Kv).x, fmaf((Qv).y, (Kv).y, fmaf((Qv).z, (Kv).z, fmaf((Qv).w, (Kv).w, (A)))))

__launch_bounds__(256, 2)
__global__ void entmax_fallback_kernel(const float* __restrict__ Q,
                                       const float* __restrict__ V,
                                       const float* __restrict__ K,
                                       float* __restrict__ Out) {
    extern __shared__ float zshf[];
    const int tid = threadIdx.x;
    const int b   = blockIdx.x >> 8;
    const int t0  = (blockIdx.x & 255) * 8;
    const float* Qb = Q + ((size_t)b * TT + t0) * DD;
    const float* Kb = K + (size_t)b * TT * DD;
    const float* Vb = V + (size_t)b * TT * DD;
    for (int g = 0; g < 2; ++g) {
        const int c0 = (g << 10) + tid;
        const float* k0 = Kb + (size_t)c0 * DD;
        float4 acc[8];
        #pragma unroll
        for (int r = 0; r < 8; ++r) acc[r] = make_float4(0.f, 0.f, 0.f, 0.f);
        for (int d = 0; d < DD; d += 4) {
            const float4 ka = *(const float4*)(k0 + d);
            const float4 kb = *(const float4*)(k0 + 256 * DD + d);
            const float4 kc = *(const float4*)(k0 + 512 * DD + d);
            const float4 kd = *(const float4*)(k0 + 768 * DD + d);
            #pragma unroll
            for (int r = 0; r < 8; ++r) {
                const float4 qv = *(const float4*)(Qb + r * DD + d);
                DOT4(acc[r].x, ka, qv); DOT4(acc[r].y, kb, qv);
                DOT4(acc[r].z, kc, qv); DOT4(acc[r].w, kd, qv);
            }
        }
        #pragma unroll
        for (int r = 0; r < 8; ++r) {
            zshf[r * TT + c0      ] = 0.5f * acc[r].x;
            zshf[r * TT + c0 + 256] = 0.5f * acc[r].y;
            zshf[r * TT + c0 + 512] = 0.5f * acc[r].z;
            zshf[r * TT + c0 + 768] = 0.5f * acc[r].w;
        }
    }
    __syncthreads();
    {
        const int wid = tid >> 6, lane = tid & 63;
        for (int rr = 0; rr < 2; ++rr) {
            const int r = wid * 2 + rr;
            float* z = zshf + r * TT;
            float zv[32];
            float m = -3.402823466e38f;
            #pragma unroll
            for (int j = 0; j < 32; ++j) { zv[j] = z[lane + (j << 6)]; m = fmaxf(m, zv[j]); }
            #pragma unroll
            for (int off = 32; off; off >>= 1) m = fmaxf(m, __shfl_xor(m, off));
            float lo = m - 1.0f, hi = m;
            for (int it = 0; it < NITER; ++it) {
                const float tau = 0.5f * (lo + hi);
                float s = 0.f;
                #pragma unroll
                for (int j = 0; j < 32; ++j) { float t = fmaxf(zv[j] - tau, 0.f); s = fmaf(t, t, s); }
                #pragma unroll
                for (int off = 32; off; off >>= 1) s += __shfl_xor(s, off);
                const bool gt = (s - 1.0f) > 0.0f;
                lo = gt ? tau : lo; hi = gt ? hi : tau;
            }
            const float tau = 0.5f * (lo + hi);
            float ssum = 0.f;
            #pragma unroll
            for (int j = 0; j < 32; ++j) { float t = fmaxf(zv[j] - tau, 0.f); ssum = fmaf(t, t, ssum); }
            #pragma unroll
            for (int off = 32; off; off >>= 1) ssum += __shfl_xor(ssum, off);
            const float inv = 1.0f / ssum;
            #pragma unroll
            for (int j = 0; j < 32; ++j) {
                float t = fmaxf(zv[j] - tau, 0.f);
                z[lane + (j << 6)] = t * t * inv;
            }
        }
    }
    __syncthreads();
    {
        const int d2 = (tid & 127) * 2;
        const int sg = tid >> 7;
        float2 acc[8];
        #pragma unroll
        for (int r = 0; r < 8; ++r) acc[r] = make_float2(0.f, 0.f);
        for (int sc = 0; sc < TT; sc += 8) {
            const int s0 = sc + sg * 4;
            float4 w4[8];
            #pragma unroll
            for (int r = 0; r < 8; ++r) w4[r] = *(const float4*)&zshf[r * TT + s0];
            #pragma unroll
            for (int js = 0; js < 4; ++js) {
                const float2 v = *(const float2*)(Vb + (size_t)(s0 + js) * DD + d2);
                #pragma unroll
                for (int r = 0; r < 8; ++r) {
                    const float wv = (js == 0) ? w4[r].x : (js == 1) ? w4[r].y
                                   : (js == 2) ? w4[r].z : w4[r].w;
                    acc[r].x = fmaf(wv, v.x, acc[r].x);
                    acc[r].y = fmaf(wv, v.y, acc[r].y);
                }
            }
        }
        __syncthreads();
        float* part = zshf;
        if (sg == 1) {
            #pragma unroll
            for (int r = 0; r < 8; ++r) *(float2*)&part[r * DD + d2] = acc[r];
        }
        __syncthreads();
        if (sg == 0) {
            #pragma unroll
            for (int r = 0; r < 8; ++r) {
                const float2 p = *(const float2*)&part[r * DD + d2];
                float2 o; o.x = acc[r].x + p.x; o.y = acc[r].y + p.y;
                *(float2*)&Out[((size_t)b * TT + t0 + r) * DD + d2] = o;
            }
        }
    }
}

extern "C" void kernel_launch(void* const* d_in, const int* in_sizes, int n_in,
                              void* d_out, int out_size, void* d_ws, size_t ws_size,
                              hipStream_t stream) {
    const float* Q = (const float*)d_in[0];   // query
    const float* V = (const float*)d_in[1];   // value (dict order!)
    const float* K = (const float*)d_in[2];   // key
    float* Out = (float*)d_out;
    const int B = in_sizes[0] / (TT * DD);
    const size_t NE = (size_t)B * TT * DD;
    const size_t need = NE * 2 * 2;           // Kh + Kl (bf16 each)

    if (ws_size < need) {                     // defensive fallback (round-1 kernel)
        entmax_fallback_kernel<<<dim3(B * (TT / 8)), 256, 8 * TT * sizeof(float), stream>>>(
            Q, V, K, Out);
        return;
    }

    unsigned short* Kh = (unsigned short*)d_ws;
    unsigned short* Kl = Kh + NE;

    split_k_kernel<<<2048, 256, 0, stream>>>(K, Kh, Kl, (int)(NE / 4));
    entmax_sparse_kernel<<<dim3(B * (TT / RQ)), NT, 0, stream>>>(Q, Kh, Kl, V, Out);
}

// Round 4
// 289.506 us; speedup vs baseline: 9.2192x; 1.9779x over previous
//
#include <hip/hip_runtime.h>

#define TT 2048     // sequence length
#define DD 256      // head dim
#define RQB 128     // q-rows per block (4 waves x 32)
#define NT 256      // 4 waves
#define KB 64       // K-cols per LDS tile
#define NTILE (TT / KB)   // 32
#define NITER 30
#define CAP 32      // max candidates per row (expected ~1-3)

// LDS byte layout
#define L_CVAL 131072                  // float [RQB][CAP]
#define L_CIDX (L_CVAL + RQB * CAP * 4)      // u16 [RQB][CAP]
#define L_RMAX (L_CIDX + RQB * CAP * 2)      // float [RQB]
#define L_CNT  (L_RMAX + RQB * 4)            // int [RQB]
#define L_OVF  (L_CNT + RQB * 4)             // int
#define LDS_SZ (L_OVF + 16)

typedef __attribute__((ext_vector_type(4))) float f32x4;
typedef __attribute__((ext_vector_type(8))) short short8;

__device__ inline unsigned short f2bf(float x) {     // RTN fp32 -> bf16
    unsigned u = __float_as_uint(x);
    return (unsigned short)((u + 0x7fffu + ((u >> 16) & 1u)) >> 16);
}
__device__ inline float bf2f(unsigned short h) {
    return __uint_as_float((unsigned)h << 16);
}

__device__ __forceinline__ void gload16(const void* g, void* l) {
    __builtin_amdgcn_global_load_lds(
        (const __attribute__((address_space(1))) void*)g,
        (__attribute__((address_space(3))) void*)l, 16, 0, 0);
}

// ---------------- helper: K -> 0.5*K split to bf16 hi/lo ----------------
__global__ __launch_bounds__(256) void split_k_kernel(const float* __restrict__ K,
        unsigned short* __restrict__ Kh, unsigned short* __restrict__ Kl, int n4) {
    int i = blockIdx.x * 256 + threadIdx.x;
    const int stride = gridDim.x * 256;
    for (; i < n4; i += stride) {
        float4 v = ((const float4*)K)[i];
        float x0 = 0.5f * v.x, x1 = 0.5f * v.y, x2 = 0.5f * v.z, x3 = 0.5f * v.w;
        unsigned short h0 = f2bf(x0), h1 = f2bf(x1), h2 = f2bf(x2), h3 = f2bf(x3);
        unsigned short l0 = f2bf(x0 - bf2f(h0)), l1 = f2bf(x1 - bf2f(h1));
        unsigned short l2 = f2bf(x2 - bf2f(h2)), l3 = f2bf(x3 - bf2f(h3));
        uint2 hv, lv;
        hv.x = (unsigned)h0 | ((unsigned)h1 << 16); hv.y = (unsigned)h2 | ((unsigned)h3 << 16);
        lv.x = (unsigned)l0 | ((unsigned)l1 << 16); lv.y = (unsigned)l2 | ((unsigned)l3 << 16);
        ((uint2*)Kh)[i] = hv;
        ((uint2*)Kl)[i] = lv;
    }
}

// ---------------- main fused kernel ----------------
// ds_read of B-frag: col c (tile-local), byte d within row, both streams swizzled
#define LDSB(hl, ct, kk) \
    (*(const short8*)(smem + (size_t)(cur * 65536 + (hl) * 32768 + ((ct) * 16 + l15) * 512 + \
                      ((((kk) * 64) + ag * 16) ^ ((l15 & 7) << 4)))))

__launch_bounds__(NT, 1)
__global__ void entmax_tile_kernel(const float* __restrict__ Q,
                                   const unsigned short* __restrict__ Kh,
                                   const unsigned short* __restrict__ Kl,
                                   const float* __restrict__ V,
                                   float* __restrict__ Out,
                                   int nwg) {
    extern __shared__ char smem[];
    float*          CVAL = (float*)(smem + L_CVAL);
    unsigned short* CIDX = (unsigned short*)(smem + L_CIDX);
    float*          RMAX = (float*)(smem + L_RMAX);
    int*            CNT  = (int*)(smem + L_CNT);
    int*            POVF = (int*)(smem + L_OVF);

    const int tid = threadIdx.x;
    const int wid = tid >> 6, lane = tid & 63;
    const int l15 = lane & 15, ag = lane >> 4;

    // XCD-bijective swizzle (nwg % 8 == 0 always: nwg = B*16)
    const int lb = (blockIdx.x & 7) * (nwg >> 3) + (blockIdx.x >> 3);
    const int b  = lb >> 4;
    const int t0 = (lb & 15) * RQB;

    const char* KhB = (const char*)(Kh + (size_t)b * TT * DD);
    const char* KlB = (const char*)(Kl + (size_t)b * TT * DD);

    for (int i = tid; i < RQB; i += NT) CNT[i] = 0;
    if (tid == 0) *POVF = 0;

    // ---- A-fragments: Q rows (hi/lo bf16), held in registers for both passes ----
    short8 ah[2][8], al[2][8];
    #pragma unroll
    for (int g = 0; g < 2; ++g) {
        const float* qr = Q + (size_t)(b * TT + t0 + wid * 32 + g * 16 + l15) * DD;
        #pragma unroll
        for (int kk = 0; kk < 8; ++kk) {
            const int d0 = kk * 32 + ag * 8;
            float4 qa = *(const float4*)(qr + d0);
            float4 qb = *(const float4*)(qr + d0 + 4);
            float qf[8] = {qa.x, qa.y, qa.z, qa.w, qb.x, qb.y, qb.z, qb.w};
            #pragma unroll
            for (int i = 0; i < 8; ++i) {
                unsigned short h = f2bf(qf[i]);
                ah[g][kk][i] = (short)h;
                al[g][kk][i] = (short)f2bf(qf[i] - bf2f(h));
            }
        }
    }

    // ---- staging: wave stages its 16 cols of the tile (2 cols per call) ----
    auto STAGE = [&](int tile, int buf) {
        #pragma unroll
        for (int j = 0; j < 8; ++j) {
            const int cl = wid * 16 + 2 * j + (lane >> 5);     // tile-local col
            const int wb = (lane & 31) * 16;                    // linear LDS byte
            const size_t gb = ((size_t)(tile * KB + cl) << 9) +
                              (size_t)(wb ^ ((cl & 7) << 4));   // inverse-swizzled src
            char* lb_ = smem + buf * 65536 + (wid * 16 + 2 * j) * 512;
            gload16(KhB + gb, lb_);
            gload16(KlB + gb, lb_ + 32768);
        }
    };

#define COMPUTE_TILE() do {                                                        \
    _Pragma("unroll")                                                              \
    for (int kk = 0; kk < 8; ++kk) {                                               \
        short8 bh[4], bl[4];                                                       \
        _Pragma("unroll")                                                          \
        for (int ct = 0; ct < 4; ++ct) { bh[ct] = LDSB(0, ct, kk); bl[ct] = LDSB(1, ct, kk); } \
        _Pragma("unroll")                                                          \
        for (int g = 0; g < 2; ++g)                                                \
            _Pragma("unroll")                                                      \
            for (int ct = 0; ct < 4; ++ct) {                                       \
                acc[g][ct] = __builtin_amdgcn_mfma_f32_16x16x32_bf16(ah[g][kk], bh[ct], acc[g][ct], 0, 0, 0); \
                acc[g][ct] = __builtin_amdgcn_mfma_f32_16x16x32_bf16(ah[g][kk], bl[ct], acc[g][ct], 0, 0, 0); \
                acc[g][ct] = __builtin_amdgcn_mfma_f32_16x16x32_bf16(al[g][kk], bh[ct], acc[g][ct], 0, 0, 0); \
            }                                                                      \
    }                                                                              \
} while (0)

    // prologue: stage tile 0 into buf 0
    STAGE(0, 0);
    __syncthreads();

    float lmax[2][4];
    #pragma unroll
    for (int g = 0; g < 2; ++g)
        #pragma unroll
        for (int r = 0; r < 4; ++r) lmax[g][r] = -3.402823466e38f;

    // ---------------- Pass A: row maxima ----------------
    for (int t = 0; t < NTILE; ++t) {
        const int cur = t & 1;
        STAGE((t + 1) & (NTILE - 1), cur ^ 1);   // last iter stages tile 0 for pass B
        f32x4 acc[2][4];
        #pragma unroll
        for (int g = 0; g < 2; ++g)
            #pragma unroll
            for (int ct = 0; ct < 4; ++ct)
                #pragma unroll
                for (int r = 0; r < 4; ++r) acc[g][ct][r] = 0.0f;
        COMPUTE_TILE();
        #pragma unroll
        for (int g = 0; g < 2; ++g)
            #pragma unroll
            for (int r = 0; r < 4; ++r) {
                float m = fmaxf(fmaxf(acc[0 + g][0][r], acc[g][1][r]),
                                fmaxf(acc[g][2][r], acc[g][3][r]));
                lmax[g][r] = fmaxf(lmax[g][r], m);
            }
        __syncthreads();
    }

    // reduce lane-local maxima -> RMAX (rows are wave-private)
    float thr[2][4];
    #pragma unroll
    for (int g = 0; g < 2; ++g)
        #pragma unroll
        for (int r = 0; r < 4; ++r) {
            float m = lmax[g][r];
            m = fmaxf(m, __shfl_xor(m, 1));
            m = fmaxf(m, __shfl_xor(m, 2));
            m = fmaxf(m, __shfl_xor(m, 4));
            m = fmaxf(m, __shfl_xor(m, 8));
            if (l15 == 0) RMAX[wid * 32 + g * 16 + ag * 4 + r] = m;
            thr[g][r] = m - 1.0f;       // wave-uniform within 16-lane group
        }

    // ---------------- Pass B: recompute z, exact candidate compaction ----------------
    for (int t = 0; t < NTILE; ++t) {
        const int cur = t & 1;
        if (t + 1 < NTILE) STAGE(t + 1, cur ^ 1);
        f32x4 acc[2][4];
        #pragma unroll
        for (int g = 0; g < 2; ++g)
            #pragma unroll
            for (int ct = 0; ct < 4; ++ct)
                #pragma unroll
                for (int r = 0; r < 4; ++r) acc[g][ct][r] = 0.0f;
        COMPUTE_TILE();
        #pragma unroll
        for (int g = 0; g < 2; ++g)
            #pragma unroll
            for (int r = 0; r < 4; ++r)
                #pragma unroll
                for (int ct = 0; ct < 4; ++ct) {
                    const bool p = acc[g][ct][r] > thr[g][r];
                    const unsigned long long ball = __ballot(p);
                    if (ball) {
                        const unsigned grp = (unsigned)((ball >> (ag * 16)) & 0xFFFFu);
                        if (grp) {
                            const int row  = wid * 32 + g * 16 + ag * 4 + r;
                            const int cntg = __popc(grp);
                            const int rank = __popc(grp & ((1u << l15) - 1u));
                            const int base = CNT[row];
                            if (p && base + rank < CAP) {
                                CVAL[row * CAP + base + rank] = acc[g][ct][r];
                                CIDX[row * CAP + base + rank] =
                                    (unsigned short)(t * KB + ct * 16 + l15);
                            }
                            if (l15 == 0) {
                                const int nb = base + cntg;
                                CNT[row] = nb;
                                if (nb > CAP) *POVF = 1;
                            }
                        }
                    }
                }
        __syncthreads();
    }
    __syncthreads();

    // ---------------- Slow path (CAP overflow; ~never) ----------------
    if (*POVF) {
        if (wid == 0) {
            float* fbz = (float*)smem;          // staging area is dead now
            for (int r = 0; r < RQB; ++r) {
                if (CNT[r] <= CAP) continue;
                const float* qr = Q + (size_t)(b * TT + t0 + r) * DD;
                for (int c = lane; c < TT; c += 64) {
                    const unsigned short* ph = Kh + ((size_t)b * TT + c) * DD;
                    const unsigned short* pl = Kl + ((size_t)b * TT + c) * DD;
                    float a = 0.0f;
                    for (int d = 0; d < DD; ++d)
                        a = fmaf(qr[d], bf2f(ph[d]) + bf2f(pl[d]), a);
                    fbz[c] = a;
                }
                __threadfence_block();
                float m = -3.402823466e38f;
                for (int c = lane; c < TT; c += 64) m = fmaxf(m, fbz[c]);
                #pragma unroll
                for (int off = 32; off; off >>= 1) m = fmaxf(m, __shfl_xor(m, off));
                float lo = m - 1.0f, hi = m, tau;
                for (int it = 0; it < NITER; ++it) {
                    tau = 0.5f * (lo + hi);
                    float s = 0.0f;
                    for (int c = lane; c < TT; c += 64) {
                        float tt = fmaxf(fbz[c] - tau, 0.0f);
                        s = fmaf(tt, tt, s);
                    }
                    #pragma unroll
                    for (int off = 32; off; off >>= 1) s += __shfl_xor(s, off);
                    const bool gt = s > 1.0f;
                    lo = gt ? tau : lo;
                    hi = gt ? hi : tau;
                }
                tau = 0.5f * (lo + hi);
                float ssum = 0.0f;
                for (int c = lane; c < TT; c += 64) {
                    float tt = fmaxf(fbz[c] - tau, 0.0f);
                    ssum = fmaf(tt, tt, ssum);
                }
                #pragma unroll
                for (int off = 32; off; off >>= 1) ssum += __shfl_xor(ssum, off);
                const float inv = 1.0f / ssum;
                const int d4 = lane * 4;
                float4 o = make_float4(0.f, 0.f, 0.f, 0.f);
                for (int s = 0; s < TT; ++s) {
                    float tt = fmaxf(fbz[s] - tau, 0.0f);
                    const float w = tt * tt * inv;
                    if (w > 0.0f) {
                        const float4 v = *(const float4*)(V + ((size_t)b * TT + s) * DD + d4);
                        o.x = fmaf(w, v.x, o.x); o.y = fmaf(w, v.y, o.y);
                        o.z = fmaf(w, v.z, o.z); o.w = fmaf(w, v.w, o.w);
                    }
                }
                *(float4*)(Out + ((size_t)(b * TT + t0 + r)) * DD + d4) = o;
                if (lane == 0) CNT[r] = -1;
                __threadfence_block();
            }
        }
        __syncthreads();
    }

    // ---------------- Phase 2+3: tau, weights, sparse PV ----------------
    const float* Vb = V + (size_t)b * TT * DD;
    for (int j = 0; j < 32; ++j) {
        const int row = wid * 32 + j;
        const int n = CNT[row];
        if (n < 0) continue;
        const float cv = (lane < n) ? CVAL[row * CAP + lane] : -3.402823466e38f;
        const int   ci = (lane < n) ? (int)CIDX[row * CAP + lane] : 0;
        float tau;
        if (n == 1) {
            tau = __shfl(cv, 0) - 1.0f;
        } else if (n == 2) {
            const float a = __shfl(cv, 0), c2 = __shfl(cv, 1);
            const float hv = fmaxf(a, c2), lv = fminf(a, c2);
            const float d = hv - lv;
            tau = (d >= 1.0f) ? (hv - 1.0f)
                              : 0.5f * ((hv + lv) - sqrtf(2.0f - d * d));
        } else {
            const float m = RMAX[row];
            float lo = m - 1.0f, hi = m;
            for (int it = 0; it < NITER; ++it) {
                const float tm = 0.5f * (lo + hi);
                float tt = fmaxf(cv - tm, 0.0f);
                float s = tt * tt;
                #pragma unroll
                for (int off = 32; off; off >>= 1) s += __shfl_xor(s, off);
                const bool gt = s > 1.0f;
                lo = gt ? tm : lo;
                hi = gt ? hi : tm;
            }
            tau = 0.5f * (lo + hi);
        }
        const float tt = fmaxf(cv - tau, 0.0f);
        float s = tt * tt;
        #pragma unroll
        for (int off = 32; off; off >>= 1) s += __shfl_xor(s, off);
        const float w = tt * tt / s;
        const int d4 = lane * 4;
        float4 o = make_float4(0.f, 0.f, 0.f, 0.f);
        for (int i = 0; i < n; ++i) {
            const float wi = __shfl(w, i);
            const int   si = __shfl(ci, i);
            const float4 v = *(const float4*)(Vb + (size_t)si * DD + d4);
            o.x = fmaf(wi, v.x, o.x); o.y = fmaf(wi, v.y, o.y);
            o.z = fmaf(wi, v.z, o.z); o.w = fmaf(wi, v.w, o.w);
        }
        *(float4*)(Out + ((size_t)(b * TT + t0 + row)) * DD + d4) = o;
    }
}

// ---------------- round-1 kernel kept as ws-size fallback ----------------
#define DOT4(A, Kv, Qv) \
    A = fmaf((Qv).x, (Kv).x, fmaf((Qv).y, (Kv).y, fmaf((Qv).z, (Kv).z, fmaf((Qv).w, (Kv).w, (A)))))

__launch_bounds__(256, 2)
__global__ void entmax_fallback_kernel(const float* __restrict__ Q,
                                       const float* __restrict__ V,
                                       const float* __restrict__ K,
                                       float* __restrict__ Out) {
    extern __shared__ float zshf[];
    const int tid = threadIdx.x;
    const int b   = blockIdx.x >> 8;
    const int t0  = (blockIdx.x & 255) * 8;
    const float* Qb = Q + ((size_t)b * TT + t0) * DD;
    const float* Kb = K + (size_t)b * TT * DD;
    const float* Vb = V + (size_t)b * TT * DD;
    for (int g = 0; g < 2; ++g) {
        const int c0 = (g << 10) + tid;
        const float* k0 = Kb + (size_t)c0 * DD;
        float4 acc[8];
        #pragma unroll
        for (int r = 0; r < 8; ++r) acc[r] = make_float4(0.f, 0.f, 0.f, 0.f);
        for (int d = 0; d < DD; d += 4) {
            const float4 ka = *(const float4*)(k0 + d);
            const float4 kb = *(const float4*)(k0 + 256 * DD + d);
            const float4 kc = *(const float4*)(k0 + 512 * DD + d);
            const float4 kd = *(const float4*)(k0 + 768 * DD + d);
            #pragma unroll
            for (int r = 0; r < 8; ++r) {
                const float4 qv = *(const float4*)(Qb + r * DD + d);
                DOT4(acc[r].x, ka, qv); DOT4(acc[r].y, kb, qv);
                DOT4(acc[r].z, kc, qv); DOT4(acc[r].w, kd, qv);
            }
        }
        #pragma unroll
        for (int r = 0; r < 8; ++r) {
            zshf[r * TT + c0      ] = 0.5f * acc[r].x;
            zshf[r * TT + c0 + 256] = 0.5f * acc[r].y;
            zshf[r * TT + c0 + 512] = 0.5f * acc[r].z;
            zshf[r * TT + c0 + 768] = 0.5f * acc[r].w;
        }
    }
    __syncthreads();
    {
        const int wid = tid >> 6, lane = tid & 63;
        for (int rr = 0; rr < 2; ++rr) {
            const int r = wid * 2 + rr;
            float* z = zshf + r * TT;
            float zv[32];
            float m = -3.402823466e38f;
            #pragma unroll
            for (int j = 0; j < 32; ++j) { zv[j] = z[lane + (j << 6)]; m = fmaxf(m, zv[j]); }
            #pragma unroll
            for (int off = 32; off; off >>= 1) m = fmaxf(m, __shfl_xor(m, off));
            float lo = m - 1.0f, hi = m;
            for (int it = 0; it < NITER; ++it) {
                const float tau = 0.5f * (lo + hi);
                float s = 0.f;
                #pragma unroll
                for (int j = 0; j < 32; ++j) { float t = fmaxf(zv[j] - tau, 0.f); s = fmaf(t, t, s); }
                #pragma unroll
                for (int off = 32; off; off >>= 1) s += __shfl_xor(s, off);
                const bool gt = (s - 1.0f) > 0.0f;
                lo = gt ? tau : lo; hi = gt ? hi : tau;
            }
            const float tau = 0.5f * (lo + hi);
            float ssum = 0.f;
            #pragma unroll
            for (int j = 0; j < 32; ++j) { float t = fmaxf(zv[j] - tau, 0.f); ssum = fmaf(t, t, ssum); }
            #pragma unroll
            for (int off = 32; off; off >>= 1) ssum += __shfl_xor(ssum, off);
            const float inv = 1.0f / ssum;
            #pragma unroll
            for (int j = 0; j < 32; ++j) {
                float t = fmaxf(zv[j] - tau, 0.f);
                z[lane + (j << 6)] = t * t * inv;
            }
        }
    }
    __syncthreads();
    {
        const int d2 = (tid & 127) * 2;
        const int sg = tid >> 7;
        float2 acc[8];
        #pragma unroll
        for (int r = 0; r < 8; ++r) acc[r] = make_float2(0.f, 0.f);
        for (int sc = 0; sc < TT; sc += 8) {
            const int s0 = sc + sg * 4;
            float4 w4[8];
            #pragma unroll
            for (int r = 0; r < 8; ++r) w4[r] = *(const float4*)&zshf[r * TT + s0];
            #pragma unroll
            for (int js = 0; js < 4; ++js) {
                const float2 v = *(const float2*)(Vb + (size_t)(s0 + js) * DD + d2);
                #pragma unroll
                for (int r = 0; r < 8; ++r) {
                    const float wv = (js == 0) ? w4[r].x : (js == 1) ? w4[r].y
                                   : (js == 2) ? w4[r].z : w4[r].w;
                    acc[r].x = fmaf(wv, v.x, acc[r].x);
                    acc[r].y = fmaf(wv, v.y, acc[r].y);
                }
            }
        }
        __syncthreads();
        float* part = zshf;
        if (sg == 1) {
            #pragma unroll
            for (int r = 0; r < 8; ++r) *(float2*)&part[r * DD + d2] = acc[r];
        }
        __syncthreads();
        if (sg == 0) {
            #pragma unroll
            for (int r = 0; r < 8; ++r) {
                const float2 p = *(const float2*)&part[r * DD + d2];
                float2 o; o.x = acc[r].x + p.x; o.y = acc[r].y + p.y;
                *(float2*)&Out[((size_t)b * TT + t0 + r) * DD + d2] = o;
            }
        }
    }
}

extern "C" void kernel_launch(void* const* d_in, const int* in_sizes, int n_in,
                              void* d_out, int out_size, void* d_ws, size_t ws_size,
                              hipStream_t stream) {
    const float* Q = (const float*)d_in[0];   // query
    const float* V = (const float*)d_in[1];   // value (dict order!)
    const float* K = (const float*)d_in[2];   // key
    float* Out = (float*)d_out;
    const int B = in_sizes[0] / (TT * DD);
    const size_t NE = (size_t)B * TT * DD;
    const size_t need = NE * 2 * 2;           // Kh + Kl (bf16 each)

    if (ws_size < need) {                     // defensive fallback (round-1 kernel)
        entmax_fallback_kernel<<<dim3(B * (TT / 8)), 256, 8 * TT * sizeof(float), stream>>>(
            Q, V, K, Out);
        return;
    }

    unsigned short* Kh = (unsigned short*)d_ws;
    unsigned short* Kl = Kh + NE;

    split_k_kernel<<<2048, 256, 0, stream>>>(K, Kh, Kl, (int)(NE / 4));

    const int nwg = B * (TT / RQB);           // 256 for B=16 -> 1 block/CU
    (void)hipFuncSetAttribute((const void*)entmax_tile_kernel,
                              hipFuncAttributeMaxDynamicSharedMemorySize, LDS_SZ);
    entmax_tile_kernel<<<dim3(nwg), NT, LDS_SZ, stream>>>(Q, Kh, Kl, V, Out, nwg);
}